// Round 4
// baseline (503.695 us; speedup 1.0000x reference)
//
#include <hip/hip_runtime.h>

// AssociationLayer: masked Sinkhorn (100 iters) + mutual-argmax assignment.
// R4: dense-path VALU reduction (wall time = slowest dense block; sparsity
// gating is useless at 1 block/CU).
//  - K held as float2 ext-vectors -> v_pk_fma_f32 halves matvec issue count
//  - all divisions via v_rcp_f32 (tolerance is 4.92; we're at 4e-3)
//  - all-wave stage2: 4 threads/col (quad-aligned), scalars ubd/vbd/Su/Sv
//    computed redundantly per-thread from broadcast LDS partials, carried in
//    registers (no 4-wave serial section, no LDS scalar round-trips)
//  - dir2 partial write: rg==0-predicated float4 stores (kills sel4 cndmasks)
//  - red stride 260: stage2 column loads 2-way bank aliased (free)

typedef float v2f __attribute__((ext_vector_type(2)));

#define T_MAX   256
#define L_FLAT  (257 * 257)
#define N_ITERS 100
#define LAMBDA_F 10.0f
#define EPS_F    1e-12f
#define RS      260    // red row stride (floats)

#define QX1  0xB1   // quad_perm xor1
#define QX2  0x4E   // quad_perm xor2
#define ROR4 0x124  // row_ror:4
#define ROR8 0x128  // row_ror:8

template<int CTRL>
__device__ __forceinline__ float dpp_addf(float x) {
    int t = __builtin_amdgcn_update_dpp(0, __float_as_int(x), CTRL, 0xF, 0xF, true);
    return x + __int_as_float(t);
}
template<int CTRL>
__device__ __forceinline__ float dpp_maxf(float x) {
    int t = __builtin_amdgcn_update_dpp(0, __float_as_int(x), CTRL, 0xF, 0xF, true);
    return fmaxf(x, __int_as_float(t));
}
template<int CTRL>
__device__ __forceinline__ int dpp_ori(int x) {
    int t = __builtin_amdgcn_update_dpp(0, x, CTRL, 0xF, 0xF, true);
    return x | t;
}
__device__ __forceinline__ float swz16_addf(float x) {
    return x + __int_as_float(__builtin_amdgcn_ds_swizzle(__float_as_int(x), 0x401F));
}
__device__ __forceinline__ float swz16_maxf(float x) {
    return fmaxf(x, __int_as_float(__builtin_amdgcn_ds_swizzle(__float_as_int(x), 0x401F)));
}
__device__ __forceinline__ int swz16_ori(int x) {
    return x | __builtin_amdgcn_ds_swizzle(x, 0x401F);
}
__device__ __forceinline__ float fast_rcp(float x) {
#if __has_builtin(__builtin_amdgcn_rcpf)
    return __builtin_amdgcn_rcpf(x);
#else
    return 1.0f / x;
#endif
}

__global__ __launch_bounds__(1024) void assoc_sinkhorn_kernel(
    const float* __restrict__ aff,
    const int*   __restrict__ ndet,
    const int*   __restrict__ ntrk,
    float*       __restrict__ out_t,
    float*       __restrict__ out_a)
{
    const int b   = blockIdx.x;
    const int nd  = ndet[b];
    const int nt  = ntrk[b];
    const int tid = threadIdx.x;
    const int w   = tid >> 6;     // wave 0..15 -> rows 16w..16w+15
    const int l   = tid & 63;
    const int rg  = l & 3;        // row subgroup (quad axis)
    const int cg  = l >> 2;       // col group 0..15
    const int R0  = (w << 4) + (rg << 2);  // lane's 4 rows
    const int C0  = cg << 4;               // lane's 16 cols

    __shared__ __align__(16) float red[16 * RS];   // 16.6 KB partials
    __shared__ __align__(16) float varr[256];
    __shared__ __align__(16) float cmax_s[256];
    __shared__ __align__(16) float supart[16];
    __shared__ __align__(16) float svpart[2][16];

    const float ndf = (float)nd;
    const float ntf = (float)nt;

    // ---- load K = exp(lambda*aff) masked to interior, as float2 pairs ----
    v2f K2[4][8];
    {
        const float* Ab = aff + (size_t)b * (T_MAX * T_MAX);
        #pragma unroll
        for (int i = 0; i < 4; ++i) {
            const int r = R0 + i;
            const float* row = Ab + (size_t)r * T_MAX + C0;
            #pragma unroll
            for (int k = 0; k < 4; ++k) {
                const float4 x = *reinterpret_cast<const float4*>(row + 4 * k);
                const bool rv = (r < nt);
                const float e0 = (rv && (C0 + 4*k + 0) < nd) ? expf(LAMBDA_F * x.x) : 0.0f;
                const float e1 = (rv && (C0 + 4*k + 1) < nd) ? expf(LAMBDA_F * x.y) : 0.0f;
                const float e2 = (rv && (C0 + 4*k + 2) < nd) ? expf(LAMBDA_F * x.z) : 0.0f;
                const float e3 = (rv && (C0 + 4*k + 3) < nd) ? expf(LAMBDA_F * x.w) : 0.0f;
                K2[i][2*k + 0] = (v2f){e0, e1};
                K2[i][2*k + 1] = (v2f){e2, e3};
            }
        }
    }

    if (tid < 256) varr[tid] = (tid < nd) ? 1.0f : 0.0f;
    if (tid < 16)  svpart[0][tid] = (tid == 0) ? ndf : 0.0f;
    __syncthreads();

    float u[4] = {0.f, 0.f, 0.f, 0.f};
    float vbd = 1.0f;   // v[nd], register-carried, identical in all threads
    float ubd = 0.0f;   // u[nt]

    const int s2c   = (w << 4) + (l >> 2);  // stage2 column of this thread
    const int s2sub = l & 3;                // stage2 partial-subset index

    for (int it = 0; it < N_ITERS; ++it) {
        // ============ phase1: u update (wave-local) + dir2 partials ============
        v2f v2[8];
        {
            const float4 a0 = *reinterpret_cast<const float4*>(&varr[C0]);
            const float4 a1 = *reinterpret_cast<const float4*>(&varr[C0 + 4]);
            const float4 a2 = *reinterpret_cast<const float4*>(&varr[C0 + 8]);
            const float4 a3 = *reinterpret_cast<const float4*>(&varr[C0 + 12]);
            v2[0] = (v2f){a0.x, a0.y}; v2[1] = (v2f){a0.z, a0.w};
            v2[2] = (v2f){a1.x, a1.y}; v2[3] = (v2f){a1.z, a1.w};
            v2[4] = (v2f){a2.x, a2.y}; v2[5] = (v2f){a2.z, a2.w};
            v2[6] = (v2f){a3.x, a3.y}; v2[7] = (v2f){a3.z, a3.w};
        }
        float p[4];
        #pragma unroll
        for (int i = 0; i < 4; ++i) {
            v2f s2 = K2[i][0] * v2[0];
            #pragma unroll
            for (int jj = 1; jj < 8; ++jj)
                s2 = __builtin_elementwise_fma(K2[i][jj], v2[jj], s2);
            p[i] = s2.x + s2.y;
        }
        #pragma unroll
        for (int i = 0; i < 4; ++i) p[i] = dpp_addf<ROR4>(p[i]);
        #pragma unroll
        for (int i = 0; i < 4; ++i) p[i] = dpp_addf<ROR8>(p[i]);
        #pragma unroll
        for (int i = 0; i < 4; ++i) p[i] = swz16_addf(p[i]);
        #pragma unroll
        for (int i = 0; i < 4; ++i) p[i] += __shfl_xor(p[i], 32, 64);
        const float vbdE = vbd + EPS_F;
        #pragma unroll
        for (int i = 0; i < 4; ++i)
            u[i] = ((R0 + i) < nt) ? fast_rcp(p[i] + vbdE) : 0.0f;

        // wave Sigma(u) -> supart[w]
        {
            float su = (u[0] + u[1]) + (u[2] + u[3]);
            su = dpp_addf<QX1>(su);
            su = dpp_addf<QX2>(su);
            if (l == 0) supart[w] = su;
        }

        // dir2: K^T @ u partials, quad-reduced over rg
        v2f q2[8];
        {
            const v2f u0 = (v2f){u[0], u[0]};
            #pragma unroll
            for (int jj = 0; jj < 8; ++jj) q2[jj] = K2[0][jj] * u0;
            #pragma unroll
            for (int i = 1; i < 4; ++i) {
                const v2f ui = (v2f){u[i], u[i]};
                #pragma unroll
                for (int jj = 0; jj < 8; ++jj)
                    q2[jj] = __builtin_elementwise_fma(K2[i][jj], ui, q2[jj]);
            }
        }
        float q[16];
        #pragma unroll
        for (int jj = 0; jj < 8; ++jj) { q[2*jj] = q2[jj].x; q[2*jj + 1] = q2[jj].y; }
        #pragma unroll
        for (int j = 0; j < 16; ++j) q[j] = dpp_addf<QX1>(q[j]);
        #pragma unroll
        for (int j = 0; j < 16; ++j) q[j] = dpp_addf<QX2>(q[j]);
        if (rg == 0) {
            float* dst = &red[w * RS + C0];
            *reinterpret_cast<float4*>(dst)      = make_float4(q[0],  q[1],  q[2],  q[3]);
            *reinterpret_cast<float4*>(dst + 4)  = make_float4(q[4],  q[5],  q[6],  q[7]);
            *reinterpret_cast<float4*>(dst + 8)  = make_float4(q[8],  q[9],  q[10], q[11]);
            *reinterpret_cast<float4*>(dst + 12) = make_float4(q[12], q[13], q[14], q[15]);
        }
        __syncthreads();   // barrier A

        // ============ stage2: v update (all waves, 4 threads/col) ============
        {
            const int p_rd = it & 1;
            float s0 = red[(4*s2sub + 0) * RS + s2c];
            float s1 = red[(4*s2sub + 1) * RS + s2c];
            float s2 = red[(4*s2sub + 2) * RS + s2c];
            float s3 = red[(4*s2sub + 3) * RS + s2c];
            float s = (s0 + s1) + (s2 + s3);
            s = dpp_addf<QX1>(s);
            s = dpp_addf<QX2>(s);   // full col sum in every quad lane

            const float4 a0 = *reinterpret_cast<const float4*>(&supart[0]);
            const float4 a1 = *reinterpret_cast<const float4*>(&supart[4]);
            const float4 a2 = *reinterpret_cast<const float4*>(&supart[8]);
            const float4 a3 = *reinterpret_cast<const float4*>(&supart[12]);
            const float Su = (((a0.x+a0.y)+(a0.z+a0.w)) + ((a1.x+a1.y)+(a1.z+a1.w)))
                           + (((a2.x+a2.y)+(a2.z+a2.w)) + ((a3.x+a3.y)+(a3.z+a3.w)));
            const float4 b0 = *reinterpret_cast<const float4*>(&svpart[p_rd][0]);
            const float4 b1 = *reinterpret_cast<const float4*>(&svpart[p_rd][4]);
            const float4 b2 = *reinterpret_cast<const float4*>(&svpart[p_rd][8]);
            const float4 b3 = *reinterpret_cast<const float4*>(&svpart[p_rd][12]);
            const float Sv = (((b0.x+b0.y)+(b0.z+b0.w)) + ((b1.x+b1.y)+(b1.z+b1.w)))
                           + (((b2.x+b2.y)+(b2.z+b2.w)) + ((b3.x+b3.y)+(b3.z+b3.w)));

            const float ubd_new = ndf * fast_rcp(Sv + vbd + EPS_F);
            const float vn = (s2c < nd) ? fast_rcp(s + ubd_new + EPS_F) : 0.0f;
            if (s2sub == 0) varr[s2c] = vn;
            vbd = ntf * fast_rcp(Su + ubd_new + EPS_F);
            ubd = ubd_new;

            // wave Sigma(v) partial -> svpart[write parity]
            float x = (s2sub == 0) ? vn : 0.0f;
            x = dpp_addf<ROR4>(x);
            x = dpp_addf<ROR8>(x);
            x = swz16_addf(x);
            x += __shfl_xor(x, 32, 64);
            if (l == 0) svpart[p_rd ^ 1][w] = x;
        }
        __syncthreads();   // barrier B
    }

    // ================= epilogue =================
    v2f v2[8];
    {
        const float4 a0 = *reinterpret_cast<const float4*>(&varr[C0]);
        const float4 a1 = *reinterpret_cast<const float4*>(&varr[C0 + 4]);
        const float4 a2 = *reinterpret_cast<const float4*>(&varr[C0 + 8]);
        const float4 a3 = *reinterpret_cast<const float4*>(&varr[C0 + 12]);
        v2[0] = (v2f){a0.x, a0.y}; v2[1] = (v2f){a0.z, a0.w};
        v2[2] = (v2f){a1.x, a1.y}; v2[3] = (v2f){a1.z, a1.w};
        v2[4] = (v2f){a2.x, a2.y}; v2[5] = (v2f){a2.z, a2.w};
        v2[6] = (v2f){a3.x, a3.y}; v2[7] = (v2f){a3.z, a3.w};
    }
    // t = u*K*v (overwrite K2)
    #pragma unroll
    for (int i = 0; i < 4; ++i) {
        const v2f ui = (v2f){u[i], u[i]};
        #pragma unroll
        for (int jj = 0; jj < 8; ++jj) K2[i][jj] = ui * K2[i][jj] * v2[jj];
    }

    // rowmax (in-wave)
    float m[4];
    #pragma unroll
    for (int i = 0; i < 4; ++i) {
        v2f mm2 = __builtin_elementwise_max(K2[i][0], K2[i][1]);
        #pragma unroll
        for (int jj = 2; jj < 8; ++jj) mm2 = __builtin_elementwise_max(mm2, K2[i][jj]);
        m[i] = fmaxf(mm2.x, mm2.y);
    }
    #pragma unroll
    for (int i = 0; i < 4; ++i) m[i] = dpp_maxf<ROR4>(m[i]);
    #pragma unroll
    for (int i = 0; i < 4; ++i) m[i] = dpp_maxf<ROR8>(m[i]);
    #pragma unroll
    for (int i = 0; i < 4; ++i) m[i] = swz16_maxf(m[i]);
    #pragma unroll
    for (int i = 0; i < 4; ++i) m[i] = fmaxf(m[i], __shfl_xor(m[i], 32, 64));

    // colmax: quad-reduce, rg==0 writes partial row
    {
        float cmx[16];
        #pragma unroll
        for (int jj = 0; jj < 8; ++jj) {
            v2f c2 = __builtin_elementwise_max(
                         __builtin_elementwise_max(K2[0][jj], K2[1][jj]),
                         __builtin_elementwise_max(K2[2][jj], K2[3][jj]));
            cmx[2*jj] = c2.x; cmx[2*jj + 1] = c2.y;
        }
        #pragma unroll
        for (int j = 0; j < 16; ++j) cmx[j] = dpp_maxf<QX1>(cmx[j]);
        #pragma unroll
        for (int j = 0; j < 16; ++j) cmx[j] = dpp_maxf<QX2>(cmx[j]);
        if (rg == 0) {
            float* dst = &red[w * RS + C0];
            *reinterpret_cast<float4*>(dst)      = make_float4(cmx[0],  cmx[1],  cmx[2],  cmx[3]);
            *reinterpret_cast<float4*>(dst + 4)  = make_float4(cmx[4],  cmx[5],  cmx[6],  cmx[7]);
            *reinterpret_cast<float4*>(dst + 8)  = make_float4(cmx[8],  cmx[9],  cmx[10], cmx[11]);
            *reinterpret_cast<float4*>(dst + 12) = make_float4(cmx[12], cmx[13], cmx[14], cmx[15]);
        }
    }
    __syncthreads();
    if (tid < 256) {
        float mm = red[tid];
        #pragma unroll
        for (int k = 1; k < 16; ++k) mm = fmaxf(mm, red[k * RS + tid]);
        cmax_s[tid] = mm;
    }
    __syncthreads();

    // mutual argmax bits
    float cm[16];
    {
        const float4 a0 = *reinterpret_cast<const float4*>(&cmax_s[C0]);
        const float4 a1 = *reinterpret_cast<const float4*>(&cmax_s[C0 + 4]);
        const float4 a2 = *reinterpret_cast<const float4*>(&cmax_s[C0 + 8]);
        const float4 a3 = *reinterpret_cast<const float4*>(&cmax_s[C0 + 12]);
        cm[0]=a0.x; cm[1]=a0.y; cm[2]=a0.z; cm[3]=a0.w;
        cm[4]=a1.x; cm[5]=a1.y; cm[6]=a1.z; cm[7]=a1.w;
        cm[8]=a2.x; cm[9]=a2.y; cm[10]=a2.z; cm[11]=a2.w;
        cm[12]=a3.x; cm[13]=a3.y; cm[14]=a3.z; cm[15]=a3.w;
    }
    unsigned bits[4];
    #pragma unroll
    for (int i = 0; i < 4; ++i) {
        unsigned bi = 0;
        const int r = R0 + i;
        #pragma unroll
        for (int jj = 0; jj < 8; ++jj) {
            const float kx = K2[i][jj].x, ky = K2[i][jj].y;
            const int c0j = C0 + 2*jj, c1j = C0 + 2*jj + 1;
            if ((r < nt) && (c0j < nd) && (kx == m[i]) && (kx == cm[2*jj]))     bi |= (1u << (2*jj));
            if ((r < nt) && (c1j < nd) && (ky == m[i]) && (ky == cm[2*jj + 1])) bi |= (1u << (2*jj + 1));
        }
        bits[i] = bi;
    }
    // rhas (in-wave OR)
    int rh[4];
    #pragma unroll
    for (int i = 0; i < 4; ++i) rh[i] = bits[i] ? 1 : 0;
    #pragma unroll
    for (int i = 0; i < 4; ++i) rh[i] = dpp_ori<ROR4>(rh[i]);
    #pragma unroll
    for (int i = 0; i < 4; ++i) rh[i] = dpp_ori<ROR8>(rh[i]);
    #pragma unroll
    for (int i = 0; i < 4; ++i) rh[i] = swz16_ori(rh[i]);
    #pragma unroll
    for (int i = 0; i < 4; ++i) rh[i] |= __shfl_xor(rh[i], 32, 64);

    // chas: quad-reduce OR (as float), rg==0 writes partial row
    {
        const unsigned anyb = bits[0] | bits[1] | bits[2] | bits[3];
        float ch[16];
        #pragma unroll
        for (int j = 0; j < 16; ++j) ch[j] = ((anyb >> j) & 1u) ? 1.0f : 0.0f;
        #pragma unroll
        for (int j = 0; j < 16; ++j) ch[j] = dpp_maxf<QX1>(ch[j]);
        #pragma unroll
        for (int j = 0; j < 16; ++j) ch[j] = dpp_maxf<QX2>(ch[j]);
        if (rg == 0) {
            float* dst = &red[w * RS + C0];
            *reinterpret_cast<float4*>(dst)      = make_float4(ch[0],  ch[1],  ch[2],  ch[3]);
            *reinterpret_cast<float4*>(dst + 4)  = make_float4(ch[4],  ch[5],  ch[6],  ch[7]);
            *reinterpret_cast<float4*>(dst + 8)  = make_float4(ch[8],  ch[9],  ch[10], ch[11]);
            *reinterpret_cast<float4*>(dst + 12) = make_float4(ch[12], ch[13], ch[14], ch[15]);
        }
    }
    __syncthreads();

    float* Ot = out_t + (size_t)b * L_FLAT;
    float* Oa = out_a + (size_t)b * L_FLAT;
    const int stride = nd + 1;

    // births row (r = nt) + corner
    if (tid < 256) {
        float c = red[tid];
        #pragma unroll
        for (int k = 1; k < 16; ++k) c = fmaxf(c, red[k * RS + tid]);
        if (tid < nd) {
            const int kk = nt * stride + tid;
            Ot[kk] = ubd * varr[tid];
            Oa[kk] = (c > 0.0f) ? 0.0f : 1.0f;
        }
    }
    if (tid == 0) {
        const int kk = nt * stride + nd;
        Ot[kk] = ubd * vbd;
        Oa[kk] = 0.0f;
    }
    // deaths column (c = nd): lanes cg==0 own rows R0..R0+3 uniquely
    if (cg == 0) {
        #pragma unroll
        for (int i = 0; i < 4; ++i) {
            const int r = R0 + i;
            if (r < nt) {
                const int kk = r * stride + nd;
                Ot[kk] = u[i] * vbd;
                Oa[kk] = rh[i] ? 0.0f : 1.0f;
            }
        }
    }
    // interior
    #pragma unroll
    for (int i = 0; i < 4; ++i) {
        const int r = R0 + i;
        if (r < nt) {
            const int base = r * stride;
            #pragma unroll
            for (int jj = 0; jj < 8; ++jj) {
                const int c0j = C0 + 2*jj, c1j = c0j + 1;
                if (c0j < nd) {
                    Ot[base + c0j] = K2[i][jj].x;
                    Oa[base + c0j] = ((bits[i] >> (2*jj)) & 1u) ? 1.0f : 0.0f;
                }
                if (c1j < nd) {
                    Ot[base + c1j] = K2[i][jj].y;
                    Oa[base + c1j] = ((bits[i] >> (2*jj + 1)) & 1u) ? 1.0f : 0.0f;
                }
            }
        }
    }
    // zero-fill padding [length, L_FLAT)
    const int length = (nt + 1) * stride;
    for (int k = length + tid; k < L_FLAT; k += 1024) {
        Ot[k] = 0.0f;
        Oa[k] = 0.0f;
    }
}

extern "C" void kernel_launch(void* const* d_in, const int* in_sizes, int n_in,
                              void* d_out, int out_size, void* d_ws, size_t ws_size,
                              hipStream_t stream)
{
    const float* aff  = (const float*)d_in[0];
    const int*   ndet = (const int*)d_in[1];
    const int*   ntrk = (const int*)d_in[2];
    const int    Bn   = in_sizes[1];
    float* out_t = (float*)d_out;
    float* out_a = out_t + (size_t)Bn * L_FLAT;
    assoc_sinkhorn_kernel<<<dim3(Bn), dim3(1024), 0, stream>>>(aff, ndet, ntrk, out_t, out_a);
}

// Round 5
// 494.297 us; speedup vs baseline: 1.0190x; 1.0190x over previous
//
#include <hip/hip_runtime.h>

// AssociationLayer: masked Sinkhorn (100 iters) + mutual-argmax assignment.
// R5 = R3 structure (scalar fp32 K[4][16]/lane, wave owns 16 rows) with:
//  - __launch_bounds__(1024,4): allow 128 arch VGPRs so K stays in VGPRs
//    (R3/R4 allocated 64V+64A and paid v_accvgpr_read on every K use)
//  - v_rcp_f32 for all divides (R4 validated: absmax 2.4e-4 vs thr 4.92)
//  - all-wave stage2: 4 threads/col via quads; ubd/vbd/Su/Sv computed
//    redundantly per-thread from broadcast LDS partials (no serial waves,
//    no LDS scalar round-trips); Su/Sv via 4 reads + quad-reduce
//  - dir2 partial write: rg==0-predicated float4 stores (no sel4 cndmasks)
//  - NO float2 packing (R4: register-pair pressure -> scratch spill,
//    +90MB HBM, 383us)

#define T_MAX   256
#define L_FLAT  (257 * 257)
#define N_ITERS 100
#define LAMBDA_F 10.0f
#define EPS_F    1e-12f
#define RS      260    // red row stride (floats)

#define QX1  0xB1   // quad_perm xor1
#define QX2  0x4E   // quad_perm xor2
#define ROR4 0x124  // row_ror:4
#define ROR8 0x128  // row_ror:8

template<int CTRL>
__device__ __forceinline__ float dpp_addf(float x) {
    int t = __builtin_amdgcn_update_dpp(0, __float_as_int(x), CTRL, 0xF, 0xF, true);
    return x + __int_as_float(t);
}
template<int CTRL>
__device__ __forceinline__ float dpp_maxf(float x) {
    int t = __builtin_amdgcn_update_dpp(0, __float_as_int(x), CTRL, 0xF, 0xF, true);
    return fmaxf(x, __int_as_float(t));
}
template<int CTRL>
__device__ __forceinline__ int dpp_ori(int x) {
    int t = __builtin_amdgcn_update_dpp(0, x, CTRL, 0xF, 0xF, true);
    return x | t;
}
__device__ __forceinline__ float swz16_addf(float x) {
    return x + __int_as_float(__builtin_amdgcn_ds_swizzle(__float_as_int(x), 0x401F));
}
__device__ __forceinline__ float swz16_maxf(float x) {
    return fmaxf(x, __int_as_float(__builtin_amdgcn_ds_swizzle(__float_as_int(x), 0x401F)));
}
__device__ __forceinline__ int swz16_ori(int x) {
    return x | __builtin_amdgcn_ds_swizzle(x, 0x401F);
}
__device__ __forceinline__ float fast_rcp(float x) {
#if __has_builtin(__builtin_amdgcn_rcpf)
    return __builtin_amdgcn_rcpf(x);
#else
    return 1.0f / x;
#endif
}

__global__ __launch_bounds__(1024, 4) void assoc_sinkhorn_kernel(
    const float* __restrict__ aff,
    const int*   __restrict__ ndet,
    const int*   __restrict__ ntrk,
    float*       __restrict__ out_t,
    float*       __restrict__ out_a)
{
    const int b   = blockIdx.x;
    const int nd  = ndet[b];
    const int nt  = ntrk[b];
    const int tid = threadIdx.x;
    const int w   = tid >> 6;     // wave 0..15 -> rows 16w..16w+15
    const int l   = tid & 63;
    const int rg  = l & 3;        // row subgroup (quad axis)
    const int cg  = l >> 2;       // col group 0..15
    const int R0  = (w << 4) + (rg << 2);  // lane's 4 rows
    const int C0  = cg << 4;               // lane's 16 cols

    __shared__ __align__(16) float red[16 * RS];   // 16.6 KB partials
    __shared__ __align__(16) float varr[256];
    __shared__ __align__(16) float cmax_s[256];
    __shared__ __align__(16) float supart[16];
    __shared__ __align__(16) float svpart[2][16];

    const float ndf = (float)nd;
    const float ntf = (float)nt;

    // ---- load K = exp(lambda*aff), masked to interior ----
    float K[4][16];
    {
        const float* Ab = aff + (size_t)b * (T_MAX * T_MAX);
        #pragma unroll
        for (int i = 0; i < 4; ++i) {
            const int r = R0 + i;
            const bool rv = (r < nt);
            const float* row = Ab + (size_t)r * T_MAX + C0;
            #pragma unroll
            for (int k = 0; k < 4; ++k) {
                const float4 x = *reinterpret_cast<const float4*>(row + 4 * k);
                const float a4[4] = {x.x, x.y, x.z, x.w};
                #pragma unroll
                for (int e = 0; e < 4; ++e) {
                    const int j = 4 * k + e;
                    K[i][j] = (rv && (C0 + j) < nd) ? expf(LAMBDA_F * a4[e]) : 0.0f;
                }
            }
        }
    }

    if (tid < 256) varr[tid] = (tid < nd) ? 1.0f : 0.0f;
    if (tid < 16)  svpart[0][tid] = (tid == 0) ? ndf : 0.0f;
    __syncthreads();

    float u[4] = {0.f, 0.f, 0.f, 0.f};
    float vbd = 1.0f;   // v[nd], register-carried, identical in all threads
    float ubd = 0.0f;   // u[nt]

    const int s2c   = (w << 4) + (l >> 2);  // stage2 column of this thread
    const int s2sub = l & 3;                // stage2 partial-subset index

    for (int it = 0; it < N_ITERS; ++it) {
        // ============ phase1: u update (wave-local) + dir2 partials ============
        float v[16];
        {
            const float4 a0 = *reinterpret_cast<const float4*>(&varr[C0]);
            const float4 a1 = *reinterpret_cast<const float4*>(&varr[C0 + 4]);
            const float4 a2 = *reinterpret_cast<const float4*>(&varr[C0 + 8]);
            const float4 a3 = *reinterpret_cast<const float4*>(&varr[C0 + 12]);
            v[0]=a0.x; v[1]=a0.y; v[2]=a0.z; v[3]=a0.w;
            v[4]=a1.x; v[5]=a1.y; v[6]=a1.z; v[7]=a1.w;
            v[8]=a2.x; v[9]=a2.y; v[10]=a2.z; v[11]=a2.w;
            v[12]=a3.x; v[13]=a3.y; v[14]=a3.z; v[15]=a3.w;
        }
        float p[4];
        #pragma unroll
        for (int i = 0; i < 4; ++i) {
            float s = 0.f;
            #pragma unroll
            for (int j = 0; j < 16; ++j) s = fmaf(K[i][j], v[j], s);
            p[i] = s;
        }
        #pragma unroll
        for (int i = 0; i < 4; ++i) p[i] = dpp_addf<ROR4>(p[i]);
        #pragma unroll
        for (int i = 0; i < 4; ++i) p[i] = dpp_addf<ROR8>(p[i]);
        #pragma unroll
        for (int i = 0; i < 4; ++i) p[i] = swz16_addf(p[i]);
        #pragma unroll
        for (int i = 0; i < 4; ++i) p[i] += __shfl_xor(p[i], 32, 64);
        const float vbdE = vbd + EPS_F;
        #pragma unroll
        for (int i = 0; i < 4; ++i)
            u[i] = ((R0 + i) < nt) ? fast_rcp(p[i] + vbdE) : 0.0f;

        // wave Sigma(u) -> supart[w]
        {
            float su = (u[0] + u[1]) + (u[2] + u[3]);
            su = dpp_addf<QX1>(su);
            su = dpp_addf<QX2>(su);
            if (l == 0) supart[w] = su;
        }

        // dir2: K^T @ u partials, quad-reduced over rg
        float q[16];
        #pragma unroll
        for (int j = 0; j < 16; ++j) {
            float s = K[0][j] * u[0];
            s = fmaf(K[1][j], u[1], s);
            s = fmaf(K[2][j], u[2], s);
            q[j] = fmaf(K[3][j], u[3], s);
        }
        #pragma unroll
        for (int j = 0; j < 16; ++j) q[j] = dpp_addf<QX1>(q[j]);
        #pragma unroll
        for (int j = 0; j < 16; ++j) q[j] = dpp_addf<QX2>(q[j]);
        if (rg == 0) {
            float* dst = &red[w * RS + C0];
            *reinterpret_cast<float4*>(dst)      = make_float4(q[0],  q[1],  q[2],  q[3]);
            *reinterpret_cast<float4*>(dst + 4)  = make_float4(q[4],  q[5],  q[6],  q[7]);
            *reinterpret_cast<float4*>(dst + 8)  = make_float4(q[8],  q[9],  q[10], q[11]);
            *reinterpret_cast<float4*>(dst + 12) = make_float4(q[12], q[13], q[14], q[15]);
        }
        __syncthreads();   // barrier A

        // ============ stage2: v update (all waves, 4 threads/col) ============
        {
            const int p_rd = it & 1;
            float s0 = red[(4*s2sub + 0) * RS + s2c];
            float s1 = red[(4*s2sub + 1) * RS + s2c];
            float s2 = red[(4*s2sub + 2) * RS + s2c];
            float s3 = red[(4*s2sub + 3) * RS + s2c];
            float s = (s0 + s1) + (s2 + s3);
            s = dpp_addf<QX1>(s);
            s = dpp_addf<QX2>(s);   // full col sum in every quad lane

            // Su: 4 broadcast reads + quad reduce (covers all 16 partials)
            float suq = (supart[4*s2sub + 0] + supart[4*s2sub + 1])
                      + (supart[4*s2sub + 2] + supart[4*s2sub + 3]);
            suq = dpp_addf<QX1>(suq);
            suq = dpp_addf<QX2>(suq);
            const float Su = suq;
            float svq = (svpart[p_rd][4*s2sub + 0] + svpart[p_rd][4*s2sub + 1])
                      + (svpart[p_rd][4*s2sub + 2] + svpart[p_rd][4*s2sub + 3]);
            svq = dpp_addf<QX1>(svq);
            svq = dpp_addf<QX2>(svq);
            const float Sv = svq;

            const float ubd_new = ndf * fast_rcp(Sv + vbd + EPS_F);
            const float vn = (s2c < nd) ? fast_rcp(s + ubd_new + EPS_F) : 0.0f;
            if (s2sub == 0) varr[s2c] = vn;
            vbd = ntf * fast_rcp(Su + ubd_new + EPS_F);
            ubd = ubd_new;

            // wave Sigma(v) partial -> svpart[write parity]
            float x = (s2sub == 0) ? vn : 0.0f;
            x = dpp_addf<ROR4>(x);
            x = dpp_addf<ROR8>(x);
            x = swz16_addf(x);
            x += __shfl_xor(x, 32, 64);
            if (l == 0) svpart[p_rd ^ 1][w] = x;
        }
        __syncthreads();   // barrier B
    }

    // ================= epilogue =================
    float v[16];
    {
        const float4 a0 = *reinterpret_cast<const float4*>(&varr[C0]);
        const float4 a1 = *reinterpret_cast<const float4*>(&varr[C0 + 4]);
        const float4 a2 = *reinterpret_cast<const float4*>(&varr[C0 + 8]);
        const float4 a3 = *reinterpret_cast<const float4*>(&varr[C0 + 12]);
        v[0]=a0.x; v[1]=a0.y; v[2]=a0.z; v[3]=a0.w;
        v[4]=a1.x; v[5]=a1.y; v[6]=a1.z; v[7]=a1.w;
        v[8]=a2.x; v[9]=a2.y; v[10]=a2.z; v[11]=a2.w;
        v[12]=a3.x; v[13]=a3.y; v[14]=a3.z; v[15]=a3.w;
    }
    // t = u*K*v (overwrite K)
    #pragma unroll
    for (int i = 0; i < 4; ++i) {
        #pragma unroll
        for (int j = 0; j < 16; ++j) K[i][j] = u[i] * K[i][j] * v[j];
    }

    // rowmax (in-wave)
    float m[4];
    #pragma unroll
    for (int i = 0; i < 4; ++i) {
        float mm = K[i][0];
        #pragma unroll
        for (int j = 1; j < 16; ++j) mm = fmaxf(mm, K[i][j]);
        m[i] = mm;
    }
    #pragma unroll
    for (int i = 0; i < 4; ++i) m[i] = dpp_maxf<ROR4>(m[i]);
    #pragma unroll
    for (int i = 0; i < 4; ++i) m[i] = dpp_maxf<ROR8>(m[i]);
    #pragma unroll
    for (int i = 0; i < 4; ++i) m[i] = swz16_maxf(m[i]);
    #pragma unroll
    for (int i = 0; i < 4; ++i) m[i] = fmaxf(m[i], __shfl_xor(m[i], 32, 64));

    // colmax: quad-reduce, rg==0 writes partial row
    {
        float cmx[16];
        #pragma unroll
        for (int j = 0; j < 16; ++j)
            cmx[j] = fmaxf(fmaxf(K[0][j], K[1][j]), fmaxf(K[2][j], K[3][j]));
        #pragma unroll
        for (int j = 0; j < 16; ++j) cmx[j] = dpp_maxf<QX1>(cmx[j]);
        #pragma unroll
        for (int j = 0; j < 16; ++j) cmx[j] = dpp_maxf<QX2>(cmx[j]);
        if (rg == 0) {
            float* dst = &red[w * RS + C0];
            *reinterpret_cast<float4*>(dst)      = make_float4(cmx[0],  cmx[1],  cmx[2],  cmx[3]);
            *reinterpret_cast<float4*>(dst + 4)  = make_float4(cmx[4],  cmx[5],  cmx[6],  cmx[7]);
            *reinterpret_cast<float4*>(dst + 8)  = make_float4(cmx[8],  cmx[9],  cmx[10], cmx[11]);
            *reinterpret_cast<float4*>(dst + 12) = make_float4(cmx[12], cmx[13], cmx[14], cmx[15]);
        }
    }
    __syncthreads();
    if (tid < 256) {
        float mm = red[tid];
        #pragma unroll
        for (int k = 1; k < 16; ++k) mm = fmaxf(mm, red[k * RS + tid]);
        cmax_s[tid] = mm;
    }
    __syncthreads();

    // mutual argmax bits
    float cm[16];
    {
        const float4 a0 = *reinterpret_cast<const float4*>(&cmax_s[C0]);
        const float4 a1 = *reinterpret_cast<const float4*>(&cmax_s[C0 + 4]);
        const float4 a2 = *reinterpret_cast<const float4*>(&cmax_s[C0 + 8]);
        const float4 a3 = *reinterpret_cast<const float4*>(&cmax_s[C0 + 12]);
        cm[0]=a0.x; cm[1]=a0.y; cm[2]=a0.z; cm[3]=a0.w;
        cm[4]=a1.x; cm[5]=a1.y; cm[6]=a1.z; cm[7]=a1.w;
        cm[8]=a2.x; cm[9]=a2.y; cm[10]=a2.z; cm[11]=a2.w;
        cm[12]=a3.x; cm[13]=a3.y; cm[14]=a3.z; cm[15]=a3.w;
    }
    unsigned bits[4];
    #pragma unroll
    for (int i = 0; i < 4; ++i) {
        unsigned bi = 0;
        const int r = R0 + i;
        #pragma unroll
        for (int j = 0; j < 16; ++j) {
            const int c = C0 + j;
            if ((r < nt) && (c < nd) && (K[i][j] == m[i]) && (K[i][j] == cm[j]))
                bi |= (1u << j);
        }
        bits[i] = bi;
    }
    // rhas (in-wave OR)
    int rh[4];
    #pragma unroll
    for (int i = 0; i < 4; ++i) rh[i] = bits[i] ? 1 : 0;
    #pragma unroll
    for (int i = 0; i < 4; ++i) rh[i] = dpp_ori<ROR4>(rh[i]);
    #pragma unroll
    for (int i = 0; i < 4; ++i) rh[i] = dpp_ori<ROR8>(rh[i]);
    #pragma unroll
    for (int i = 0; i < 4; ++i) rh[i] = swz16_ori(rh[i]);
    #pragma unroll
    for (int i = 0; i < 4; ++i) rh[i] |= __shfl_xor(rh[i], 32, 64);

    // chas: quad-reduce OR (as float), rg==0 writes partial row
    {
        const unsigned anyb = bits[0] | bits[1] | bits[2] | bits[3];
        float ch[16];
        #pragma unroll
        for (int j = 0; j < 16; ++j) ch[j] = ((anyb >> j) & 1u) ? 1.0f : 0.0f;
        #pragma unroll
        for (int j = 0; j < 16; ++j) ch[j] = dpp_maxf<QX1>(ch[j]);
        #pragma unroll
        for (int j = 0; j < 16; ++j) ch[j] = dpp_maxf<QX2>(ch[j]);
        if (rg == 0) {
            float* dst = &red[w * RS + C0];
            *reinterpret_cast<float4*>(dst)      = make_float4(ch[0],  ch[1],  ch[2],  ch[3]);
            *reinterpret_cast<float4*>(dst + 4)  = make_float4(ch[4],  ch[5],  ch[6],  ch[7]);
            *reinterpret_cast<float4*>(dst + 8)  = make_float4(ch[8],  ch[9],  ch[10], ch[11]);
            *reinterpret_cast<float4*>(dst + 12) = make_float4(ch[12], ch[13], ch[14], ch[15]);
        }
    }
    __syncthreads();

    float* Ot = out_t + (size_t)b * L_FLAT;
    float* Oa = out_a + (size_t)b * L_FLAT;
    const int stride = nd + 1;

    // births row (r = nt) + corner
    if (tid < 256) {
        float c = red[tid];
        #pragma unroll
        for (int k = 1; k < 16; ++k) c = fmaxf(c, red[k * RS + tid]);
        if (tid < nd) {
            const int kk = nt * stride + tid;
            Ot[kk] = ubd * varr[tid];
            Oa[kk] = (c > 0.0f) ? 0.0f : 1.0f;
        }
    }
    if (tid == 0) {
        const int kk = nt * stride + nd;
        Ot[kk] = ubd * vbd;
        Oa[kk] = 0.0f;
    }
    // deaths column (c = nd): lanes cg==0 own rows R0..R0+3 uniquely
    if (cg == 0) {
        #pragma unroll
        for (int i = 0; i < 4; ++i) {
            const int r = R0 + i;
            if (r < nt) {
                const int kk = r * stride + nd;
                Ot[kk] = u[i] * vbd;
                Oa[kk] = rh[i] ? 0.0f : 1.0f;
            }
        }
    }
    // interior
    #pragma unroll
    for (int i = 0; i < 4; ++i) {
        const int r = R0 + i;
        if (r < nt) {
            const int base = r * stride;
            #pragma unroll
            for (int j = 0; j < 16; ++j) {
                const int c = C0 + j;
                if (c < nd) {
                    Ot[base + c] = K[i][j];
                    Oa[base + c] = ((bits[i] >> j) & 1u) ? 1.0f : 0.0f;
                }
            }
        }
    }
    // zero-fill padding [length, L_FLAT)
    const int length = (nt + 1) * stride;
    for (int k = length + tid; k < L_FLAT; k += 1024) {
        Ot[k] = 0.0f;
        Oa[k] = 0.0f;
    }
}

extern "C" void kernel_launch(void* const* d_in, const int* in_sizes, int n_in,
                              void* d_out, int out_size, void* d_ws, size_t ws_size,
                              hipStream_t stream)
{
    const float* aff  = (const float*)d_in[0];
    const int*   ndet = (const int*)d_in[1];
    const int*   ntrk = (const int*)d_in[2];
    const int    Bn   = in_sizes[1];
    float* out_t = (float*)d_out;
    float* out_a = out_t + (size_t)Bn * L_FLAT;
    assoc_sinkhorn_kernel<<<dim3(Bn), dim3(1024), 0, stream>>>(aff, ndet, ntrk, out_t, out_a);
}

// Round 6
// 422.508 us; speedup vs baseline: 1.1922x; 1.1699x over previous
//
#include <hip/hip_runtime.h>

// AssociationLayer: masked Sinkhorn (100 iters) + mutual-argmax assignment.
// R6: 512-thread block (8 waves -> 2 waves/SIMD -> 256 VGPR/wave budget) so
// the K tile (K[8][16] = 128 floats/lane) lives entirely in ARCH VGPRs.
// R3/R5 used 1024-thread blocks: HW forces 4 waves/SIMD -> 128-reg cap ->
// compiler split 64V+64A and paid v_accvgpr_read on every K use (~2x VALU).
//  - wave w owns rows 32w..32w+31; lane (rg=l&3, cg=l>>2) owns rows
//    32w+8rg..+7, cols 16cg..+15
//  - dir1 (K@v): in-wave reduce over cg (ror4,ror8,swz16,shfl32); u in regs
//  - dir2 (K^T@u): quad-reduce over rg (xor1,xor2 DPP) -> all-64-lane
//    contiguous sel4 float4 write (R3 pattern: 0 bank conflicts)
//  - stage2: all-wave, 2 threads/col; RS=260 -> reads 2-way aliased (free),
//    writes contiguous+16B-aligned; ubd/vbd register-carried everywhere
//  - fast_rcp for all divides (validated R4/R5: absmax <= 0.004 vs thr 4.92)

#define T_MAX   256
#define L_FLAT  (257 * 257)
#define N_ITERS 100
#define LAMBDA_F 10.0f
#define EPS_F    1e-12f
#define RS      260    // red row stride (floats): mult of 4 (b128 align), !=0 mod 32

#define QX1  0xB1   // quad_perm xor1
#define QX2  0x4E   // quad_perm xor2
#define ROR4 0x124  // row_ror:4
#define ROR8 0x128  // row_ror:8

template<int CTRL>
__device__ __forceinline__ float dpp_addf(float x) {
    int t = __builtin_amdgcn_update_dpp(0, __float_as_int(x), CTRL, 0xF, 0xF, true);
    return x + __int_as_float(t);
}
template<int CTRL>
__device__ __forceinline__ float dpp_maxf(float x) {
    int t = __builtin_amdgcn_update_dpp(0, __float_as_int(x), CTRL, 0xF, 0xF, true);
    return fmaxf(x, __int_as_float(t));
}
template<int CTRL>
__device__ __forceinline__ int dpp_ori(int x) {
    int t = __builtin_amdgcn_update_dpp(0, x, CTRL, 0xF, 0xF, true);
    return x | t;
}
__device__ __forceinline__ float swz16_addf(float x) {
    return x + __int_as_float(__builtin_amdgcn_ds_swizzle(__float_as_int(x), 0x401F));
}
__device__ __forceinline__ float swz16_maxf(float x) {
    return fmaxf(x, __int_as_float(__builtin_amdgcn_ds_swizzle(__float_as_int(x), 0x401F)));
}
__device__ __forceinline__ int swz16_ori(int x) {
    return x | __builtin_amdgcn_ds_swizzle(x, 0x401F);
}
__device__ __forceinline__ float fast_rcp(float x) {
#if __has_builtin(__builtin_amdgcn_rcpf)
    return __builtin_amdgcn_rcpf(x);
#else
    return 1.0f / x;
#endif
}
__device__ __forceinline__ float sel4(float a, float b, float c, float d, int rg) {
    float lo = (rg & 1) ? b : a;
    float hi = (rg & 1) ? d : c;
    return (rg & 2) ? hi : lo;
}

__global__ __launch_bounds__(512, 2) void assoc_sinkhorn_kernel(
    const float* __restrict__ aff,
    const int*   __restrict__ ndet,
    const int*   __restrict__ ntrk,
    float*       __restrict__ out_t,
    float*       __restrict__ out_a)
{
    const int b   = blockIdx.x;
    const int nd  = ndet[b];
    const int nt  = ntrk[b];
    const int tid = threadIdx.x;
    const int w   = tid >> 6;     // wave 0..7 -> rows 32w..32w+31
    const int l   = tid & 63;
    const int rg  = l & 3;        // row subgroup (quad axis)
    const int cg  = l >> 2;       // col group 0..15
    const int R0  = (w << 5) + (rg << 3);  // lane's 8 rows
    const int C0  = cg << 4;               // lane's 16 cols

    __shared__ __align__(16) float red[8 * RS];    // 8.3 KB partials
    __shared__ __align__(16) float varr[256];
    __shared__ __align__(16) float cmax_s[256];
    __shared__ __align__(16) float supart[8];
    __shared__ __align__(16) float svpart[2][8];

    const float ndf = (float)nd;
    const float ntf = (float)nt;

    // ---- load K = exp(lambda*aff), masked to interior ----
    float K[8][16];
    {
        const float* Ab = aff + (size_t)b * (T_MAX * T_MAX);
        #pragma unroll
        for (int i = 0; i < 8; ++i) {
            const int r = R0 + i;
            const bool rv = (r < nt);
            const float* row = Ab + (size_t)r * T_MAX + C0;
            #pragma unroll
            for (int k = 0; k < 4; ++k) {
                const float4 x = *reinterpret_cast<const float4*>(row + 4 * k);
                const float a4[4] = {x.x, x.y, x.z, x.w};
                #pragma unroll
                for (int e = 0; e < 4; ++e) {
                    const int j = 4 * k + e;
                    K[i][j] = (rv && (C0 + j) < nd) ? expf(LAMBDA_F * a4[e]) : 0.0f;
                }
            }
        }
    }

    if (tid < 256) varr[tid] = (tid < nd) ? 1.0f : 0.0f;
    if (tid < 8)   svpart[0][tid] = (tid == 0) ? ndf : 0.0f;
    __syncthreads();

    float u[8];
    #pragma unroll
    for (int i = 0; i < 8; ++i) u[i] = 0.f;
    float vbd = 1.0f;   // v[nd], register-carried, identical in all threads
    float ubd = 0.0f;   // u[nt]

    const int s2c   = tid >> 1;   // stage2 column of this thread
    const int s2sub = tid & 1;    // stage2 partial-subset (rows 4*sub..+3)

    for (int it = 0; it < N_ITERS; ++it) {
        // ============ phase1: u update (wave-local) ============
        float v[16];
        {
            const float4 a0 = *reinterpret_cast<const float4*>(&varr[C0]);
            const float4 a1 = *reinterpret_cast<const float4*>(&varr[C0 + 4]);
            const float4 a2 = *reinterpret_cast<const float4*>(&varr[C0 + 8]);
            const float4 a3 = *reinterpret_cast<const float4*>(&varr[C0 + 12]);
            v[0]=a0.x; v[1]=a0.y; v[2]=a0.z; v[3]=a0.w;
            v[4]=a1.x; v[5]=a1.y; v[6]=a1.z; v[7]=a1.w;
            v[8]=a2.x; v[9]=a2.y; v[10]=a2.z; v[11]=a2.w;
            v[12]=a3.x; v[13]=a3.y; v[14]=a3.z; v[15]=a3.w;
        }
        float p[8];
        #pragma unroll
        for (int i = 0; i < 8; ++i) {
            float s = 0.f;
            #pragma unroll
            for (int j = 0; j < 16; ++j) s = fmaf(K[i][j], v[j], s);
            p[i] = s;
        }
        #pragma unroll
        for (int i = 0; i < 8; ++i) p[i] = dpp_addf<ROR4>(p[i]);
        #pragma unroll
        for (int i = 0; i < 8; ++i) p[i] = dpp_addf<ROR8>(p[i]);
        #pragma unroll
        for (int i = 0; i < 8; ++i) p[i] = swz16_addf(p[i]);
        #pragma unroll
        for (int i = 0; i < 8; ++i) p[i] += __shfl_xor(p[i], 32, 64);
        const float vbdE = vbd + EPS_F;
        #pragma unroll
        for (int i = 0; i < 8; ++i)
            u[i] = ((R0 + i) < nt) ? fast_rcp(p[i] + vbdE) : 0.0f;

        // wave Sigma(u) -> supart[w] (quad covers all 32 rows of the wave)
        {
            float su = ((u[0] + u[1]) + (u[2] + u[3])) + ((u[4] + u[5]) + (u[6] + u[7]));
            su = dpp_addf<QX1>(su);
            su = dpp_addf<QX2>(su);
            if (l == 0) supart[w] = su;
        }

        // ============ dir2: K^T @ u partials, quad-reduced over rg ============
        float q[16];
        #pragma unroll
        for (int j = 0; j < 16; ++j) {
            float s = K[0][j] * u[0];
            #pragma unroll
            for (int i = 1; i < 8; ++i) s = fmaf(K[i][j], u[i], s);
            q[j] = s;
        }
        #pragma unroll
        for (int j = 0; j < 16; ++j) q[j] = dpp_addf<QX1>(q[j]);
        #pragma unroll
        for (int j = 0; j < 16; ++j) q[j] = dpp_addf<QX2>(q[j]);
        // all 64 lanes write: lane l -> floats [4l..4l+3] of row w (contiguous)
        {
            float4 o;
            o.x = sel4(q[0], q[4], q[8],  q[12], rg);
            o.y = sel4(q[1], q[5], q[9],  q[13], rg);
            o.z = sel4(q[2], q[6], q[10], q[14], rg);
            o.w = sel4(q[3], q[7], q[11], q[15], rg);
            *reinterpret_cast<float4*>(&red[w * RS + 4 * l]) = o;
        }
        __syncthreads();   // barrier A

        // ============ stage2: v update (all waves, 2 threads/col) ============
        {
            const int p_rd = it & 1;
            float s0 = red[(4*s2sub + 0) * RS + s2c];
            float s1 = red[(4*s2sub + 1) * RS + s2c];
            float s2 = red[(4*s2sub + 2) * RS + s2c];
            float s3 = red[(4*s2sub + 3) * RS + s2c];
            float s = (s0 + s1) + (s2 + s3);
            s = dpp_addf<QX1>(s);   // pair-sum -> full col sum in both lanes

            const float4 a0 = *reinterpret_cast<const float4*>(&supart[0]);
            const float4 a1 = *reinterpret_cast<const float4*>(&supart[4]);
            const float Su = ((a0.x+a0.y)+(a0.z+a0.w)) + ((a1.x+a1.y)+(a1.z+a1.w));
            const float4 b0 = *reinterpret_cast<const float4*>(&svpart[p_rd][0]);
            const float4 b1 = *reinterpret_cast<const float4*>(&svpart[p_rd][4]);
            const float Sv = ((b0.x+b0.y)+(b0.z+b0.w)) + ((b1.x+b1.y)+(b1.z+b1.w));

            const float ubd_new = ndf * fast_rcp(Sv + vbd + EPS_F);
            const float vn = (s2c < nd) ? fast_rcp(s + ubd_new + EPS_F) : 0.0f;
            if (s2sub == 0) varr[s2c] = vn;
            vbd = ntf * fast_rcp(Su + ubd_new + EPS_F);
            ubd = ubd_new;

            // wave Sigma(v) partial (32 cols) -> svpart[write parity]
            float x = (s2sub == 0) ? vn : 0.0f;
            x = dpp_addf<QX1>(x);
            x = dpp_addf<QX2>(x);
            x = dpp_addf<ROR4>(x);
            x = dpp_addf<ROR8>(x);
            x = swz16_addf(x);
            x += __shfl_xor(x, 32, 64);
            if (l == 0) svpart[p_rd ^ 1][w] = x;
        }
        __syncthreads();   // barrier B
    }

    // ================= epilogue =================
    float v[16];
    {
        const float4 a0 = *reinterpret_cast<const float4*>(&varr[C0]);
        const float4 a1 = *reinterpret_cast<const float4*>(&varr[C0 + 4]);
        const float4 a2 = *reinterpret_cast<const float4*>(&varr[C0 + 8]);
        const float4 a3 = *reinterpret_cast<const float4*>(&varr[C0 + 12]);
        v[0]=a0.x; v[1]=a0.y; v[2]=a0.z; v[3]=a0.w;
        v[4]=a1.x; v[5]=a1.y; v[6]=a1.z; v[7]=a1.w;
        v[8]=a2.x; v[9]=a2.y; v[10]=a2.z; v[11]=a2.w;
        v[12]=a3.x; v[13]=a3.y; v[14]=a3.z; v[15]=a3.w;
    }
    // t = u*K*v (overwrite K)
    #pragma unroll
    for (int i = 0; i < 8; ++i) {
        #pragma unroll
        for (int j = 0; j < 16; ++j) K[i][j] = u[i] * K[i][j] * v[j];
    }

    // rowmax (in-wave over cg)
    float m[8];
    #pragma unroll
    for (int i = 0; i < 8; ++i) {
        float mm = K[i][0];
        #pragma unroll
        for (int j = 1; j < 16; ++j) mm = fmaxf(mm, K[i][j]);
        m[i] = mm;
    }
    #pragma unroll
    for (int i = 0; i < 8; ++i) m[i] = dpp_maxf<ROR4>(m[i]);
    #pragma unroll
    for (int i = 0; i < 8; ++i) m[i] = dpp_maxf<ROR8>(m[i]);
    #pragma unroll
    for (int i = 0; i < 8; ++i) m[i] = swz16_maxf(m[i]);
    #pragma unroll
    for (int i = 0; i < 8; ++i) m[i] = fmaxf(m[i], __shfl_xor(m[i], 32, 64));

    // colmax: in-lane over 8 rows, quad-reduce, contiguous sel4 write
    {
        float cmx[16];
        #pragma unroll
        for (int j = 0; j < 16; ++j) {
            float c = fmaxf(K[0][j], K[1][j]);
            #pragma unroll
            for (int i = 2; i < 8; ++i) c = fmaxf(c, K[i][j]);
            cmx[j] = c;
        }
        #pragma unroll
        for (int j = 0; j < 16; ++j) cmx[j] = dpp_maxf<QX1>(cmx[j]);
        #pragma unroll
        for (int j = 0; j < 16; ++j) cmx[j] = dpp_maxf<QX2>(cmx[j]);
        float4 o;
        o.x = sel4(cmx[0], cmx[4], cmx[8],  cmx[12], rg);
        o.y = sel4(cmx[1], cmx[5], cmx[9],  cmx[13], rg);
        o.z = sel4(cmx[2], cmx[6], cmx[10], cmx[14], rg);
        o.w = sel4(cmx[3], cmx[7], cmx[11], cmx[15], rg);
        *reinterpret_cast<float4*>(&red[w * RS + 4 * l]) = o;
    }
    __syncthreads();
    {
        float mm = fmaxf(fmaxf(red[(4*s2sub + 0) * RS + s2c], red[(4*s2sub + 1) * RS + s2c]),
                         fmaxf(red[(4*s2sub + 2) * RS + s2c], red[(4*s2sub + 3) * RS + s2c]));
        mm = dpp_maxf<QX1>(mm);
        if (s2sub == 0) cmax_s[s2c] = mm;
    }
    __syncthreads();

    // mutual argmax bits
    float cm[16];
    {
        const float4 a0 = *reinterpret_cast<const float4*>(&cmax_s[C0]);
        const float4 a1 = *reinterpret_cast<const float4*>(&cmax_s[C0 + 4]);
        const float4 a2 = *reinterpret_cast<const float4*>(&cmax_s[C0 + 8]);
        const float4 a3 = *reinterpret_cast<const float4*>(&cmax_s[C0 + 12]);
        cm[0]=a0.x; cm[1]=a0.y; cm[2]=a0.z; cm[3]=a0.w;
        cm[4]=a1.x; cm[5]=a1.y; cm[6]=a1.z; cm[7]=a1.w;
        cm[8]=a2.x; cm[9]=a2.y; cm[10]=a2.z; cm[11]=a2.w;
        cm[12]=a3.x; cm[13]=a3.y; cm[14]=a3.z; cm[15]=a3.w;
    }
    unsigned bits[8];
    #pragma unroll
    for (int i = 0; i < 8; ++i) {
        unsigned bi = 0;
        const int r = R0 + i;
        #pragma unroll
        for (int j = 0; j < 16; ++j) {
            const int c = C0 + j;
            if ((r < nt) && (c < nd) && (K[i][j] == m[i]) && (K[i][j] == cm[j]))
                bi |= (1u << j);
        }
        bits[i] = bi;
    }
    // rhas (in-wave OR over cg)
    int rh[8];
    #pragma unroll
    for (int i = 0; i < 8; ++i) rh[i] = bits[i] ? 1 : 0;
    #pragma unroll
    for (int i = 0; i < 8; ++i) rh[i] = dpp_ori<ROR4>(rh[i]);
    #pragma unroll
    for (int i = 0; i < 8; ++i) rh[i] = dpp_ori<ROR8>(rh[i]);
    #pragma unroll
    for (int i = 0; i < 8; ++i) rh[i] = swz16_ori(rh[i]);
    #pragma unroll
    for (int i = 0; i < 8; ++i) rh[i] |= __shfl_xor(rh[i], 32, 64);

    // chas: quad-reduce OR (as float), contiguous sel4 write
    {
        unsigned anyb = bits[0];
        #pragma unroll
        for (int i = 1; i < 8; ++i) anyb |= bits[i];
        float ch[16];
        #pragma unroll
        for (int j = 0; j < 16; ++j) ch[j] = ((anyb >> j) & 1u) ? 1.0f : 0.0f;
        #pragma unroll
        for (int j = 0; j < 16; ++j) ch[j] = dpp_maxf<QX1>(ch[j]);
        #pragma unroll
        for (int j = 0; j < 16; ++j) ch[j] = dpp_maxf<QX2>(ch[j]);
        float4 o;
        o.x = sel4(ch[0], ch[4], ch[8],  ch[12], rg);
        o.y = sel4(ch[1], ch[5], ch[9],  ch[13], rg);
        o.z = sel4(ch[2], ch[6], ch[10], ch[14], rg);
        o.w = sel4(ch[3], ch[7], ch[11], ch[15], rg);
        *reinterpret_cast<float4*>(&red[w * RS + 4 * l]) = o;
    }
    __syncthreads();

    float* Ot = out_t + (size_t)b * L_FLAT;
    float* Oa = out_a + (size_t)b * L_FLAT;
    const int stride = nd + 1;

    // births row (r = nt) + corner
    {
        float c = fmaxf(fmaxf(red[(4*s2sub + 0) * RS + s2c], red[(4*s2sub + 1) * RS + s2c]),
                        fmaxf(red[(4*s2sub + 2) * RS + s2c], red[(4*s2sub + 3) * RS + s2c]));
        c = dpp_maxf<QX1>(c);
        if (s2sub == 0 && s2c < nd) {
            const int kk = nt * stride + s2c;
            Ot[kk] = ubd * varr[s2c];
            Oa[kk] = (c > 0.0f) ? 0.0f : 1.0f;
        }
    }
    if (tid == 0) {
        const int kk = nt * stride + nd;
        Ot[kk] = ubd * vbd;
        Oa[kk] = 0.0f;
    }
    // deaths column (c = nd): lanes cg==0 own rows R0..R0+7 uniquely
    if (cg == 0) {
        #pragma unroll
        for (int i = 0; i < 8; ++i) {
            const int r = R0 + i;
            if (r < nt) {
                const int kk = r * stride + nd;
                Ot[kk] = u[i] * vbd;
                Oa[kk] = rh[i] ? 0.0f : 1.0f;
            }
        }
    }
    // interior
    #pragma unroll
    for (int i = 0; i < 8; ++i) {
        const int r = R0 + i;
        if (r < nt) {
            const int base = r * stride;
            #pragma unroll
            for (int j = 0; j < 16; ++j) {
                const int c = C0 + j;
                if (c < nd) {
                    Ot[base + c] = K[i][j];
                    Oa[base + c] = ((bits[i] >> j) & 1u) ? 1.0f : 0.0f;
                }
            }
        }
    }
    // zero-fill padding [length, L_FLAT)
    const int length = (nt + 1) * stride;
    for (int k = length + tid; k < L_FLAT; k += 512) {
        Ot[k] = 0.0f;
        Oa[k] = 0.0f;
    }
}

extern "C" void kernel_launch(void* const* d_in, const int* in_sizes, int n_in,
                              void* d_out, int out_size, void* d_ws, size_t ws_size,
                              hipStream_t stream)
{
    const float* aff  = (const float*)d_in[0];
    const int*   ndet = (const int*)d_in[1];
    const int*   ntrk = (const int*)d_in[2];
    const int    Bn   = in_sizes[1];
    float* out_t = (float*)d_out;
    float* out_a = out_t + (size_t)Bn * L_FLAT;
    assoc_sinkhorn_kernel<<<dim3(Bn), dim3(512), 0, stream>>>(aff, ndet, ntrk, out_t, out_a);
}